// Round 2
// baseline (235.596 us; speedup 1.0000x reference)
//
#include <hip/hip_runtime.h>
#include <hip/hip_bf16.h>
#include <cstdint>

#define S_LEN 2048
#define D_DIM 512
#define NROWS 8192           // B*S
#define NQKV  1536           // 3*512 output cols of the fused projection
#define QK_SCALE 0.04419417382415922f   // 1/sqrt(512)

typedef unsigned short u16;
typedef __attribute__((ext_vector_type(8))) short short8;
typedef __attribute__((ext_vector_type(4))) float floatx4;

__device__ inline floatx4 mfma16(short8 a, short8 b, floatx4 c){
  return __builtin_amdgcn_mfma_f32_16x16x32_bf16(a, b, c, 0, 0, 0);
}
__device__ inline u16 f2b(float f){
  uint32_t u = __float_as_uint(f);
  u = (u + 0x7fffu + ((u >> 16) & 1u)) >> 16;
  return (u16)u;
}
#define GLD16(g, l) __builtin_amdgcn_global_load_lds( \
    (const __attribute__((address_space(1))) void*)(g), \
    (__attribute__((address_space(3))) void*)(l), 16, 0, 0)

// ---------------------------------------------------------------- convert
__global__ void cvt_kernel(const float* __restrict__ x,
                           const float* __restrict__ Wq,
                           const float* __restrict__ Wk,
                           const float* __restrict__ Wv,
                           u16* __restrict__ xw)
{
  const int NT4 = (NROWS * D_DIM) / 4 + (NQKV * D_DIM) / 4;
  for (int i = blockIdx.x * blockDim.x + threadIdx.x; i < NT4;
       i += gridDim.x * blockDim.x) {
    int e = i * 4;
    const float* src;
    if (e < NROWS * D_DIM) {
      src = x + e;
    } else {
      int j = e - NROWS * D_DIM;
      if (j < 512 * 512)           src = Wq + j;
      else if (j < 2 * 512 * 512)  src = Wk + (j - 512 * 512);
      else                         src = Wv + (j - 2 * 512 * 512);
    }
    float4 v = *(const float4*)src;
    ushort4 o;
    o.x = f2b(v.x); o.y = f2b(v.y); o.z = f2b(v.z); o.w = f2b(v.w);
    *(ushort4*)(xw + e) = o;
  }
}

// ---------------------------------------------------------------- QKV GEMM
__launch_bounds__(256)
__global__ void qkv_gemm(const u16* __restrict__ xb,
                         const u16* __restrict__ wb,
                         const float* __restrict__ bq,
                         const float* __restrict__ bk,
                         const float* __restrict__ bv,
                         u16* __restrict__ qb,
                         u16* __restrict__ kb,
                         u16* __restrict__ vt)
{
  __shared__ alignas(16) u16 sm[16384];   // lA[128][64] @0, lB[128][64] @8192
  const int tid = threadIdx.x;
  const int l = tid & 63, w = tid >> 6;
  const int lr = l & 15, lg = l >> 4;
  const int wr = w >> 1, wc = w & 1;
  const int bn = blockIdx.x % 12, bm = blockIdx.x / 12;
  const int m0 = bm * 128, n0 = bn * 128;

  const u16* gA = xb + (size_t)(m0 + (tid >> 3)) * D_DIM + (tid & 7) * 8;
  const u16* gB = wb + (size_t)(n0 + (tid >> 3)) * D_DIM + (tid & 7) * 8;
  char* lA0 = (char*)&sm[0] + tid * 16;
  char* lB0 = (char*)&sm[8192] + tid * 16;

  floatx4 acc[4][4];
#pragma unroll
  for (int m = 0; m < 4; m++)
#pragma unroll
    for (int n = 0; n < 4; n++) acc[m][n] = 0.0f;

  for (int kt = 0; kt < 8; ++kt) {
    __syncthreads();
#pragma unroll
    for (int j = 0; j < 4; j++) {
      GLD16(gA + (size_t)j * 32 * D_DIM, lA0 + j * 4096);
      GLD16(gB + (size_t)j * 32 * D_DIM, lB0 + j * 4096);
    }
    gA += 64; gB += 64;
    __syncthreads();
#pragma unroll
    for (int kk = 0; kk < 2; ++kk) {
      short8 a[4], bfr[4];
#pragma unroll
      for (int m = 0; m < 4; m++)
        a[m] = *(const short8*)&sm[(wr * 64 + m * 16 + lr) * 64 + kk * 32 + lg * 8];
#pragma unroll
      for (int n = 0; n < 4; n++)
        bfr[n] = *(const short8*)&sm[8192 + (wc * 64 + n * 16 + lr) * 64 + kk * 32 + lg * 8];
#pragma unroll
      for (int m = 0; m < 4; m++)
#pragma unroll
        for (int n = 0; n < 4; n++)
          acc[m][n] = mfma16(a[m], bfr[n], acc[m][n]);
    }
  }

  if (n0 < 1024) {
    const float* bias = (n0 < 512) ? bq : bk;
    u16* dst = (n0 < 512) ? qb : kb;
    const float scl = (n0 < 512) ? QK_SCALE : 1.0f;
    const int nbase = n0 & 511;
#pragma unroll
    for (int n = 0; n < 4; n++) {
      int gn = nbase + wc * 64 + n * 16 + lr;
      float bia = bias[gn];
#pragma unroll
      for (int m = 0; m < 4; m++) {
        int gm0 = m0 + wr * 64 + m * 16 + lg * 4;
#pragma unroll
        for (int r = 0; r < 4; r++)
          dst[(size_t)(gm0 + r) * D_DIM + gn] = f2b((acc[m][n][r] + bia) * scl);
      }
    }
  } else {
    const int nbase = n0 - 1024;
    const int bIdx = m0 >> 11;
    const int s0 = m0 & 2047;
    __syncthreads();
#pragma unroll
    for (int h = 0; h < 2; ++h) {
      if (wc == h) {
#pragma unroll
        for (int n = 0; n < 4; n++) {
          int lrow = n * 16 + lr;
          float bia = bv[nbase + h * 64 + lrow];
#pragma unroll
          for (int m = 0; m < 4; m++) {
            int lcol = wr * 64 + m * 16 + lg * 4;
#pragma unroll
            for (int r = 0; r < 4; r++)
              sm[lrow * 136 + lcol + r] = f2b(acc[m][n][r] + bia);
          }
        }
      }
      __syncthreads();
      {
        int row = tid >> 2;
        int c0 = (tid & 3) * 32;
        u16* dstp = vt + (size_t)bIdx * D_DIM * S_LEN
                       + (size_t)(nbase + h * 64 + row) * S_LEN + s0 + c0;
        const u16* srcp = &sm[row * 136 + c0];
#pragma unroll
        for (int j = 0; j < 4; j++)
          *(short8*)(dstp + j * 8) = *(const short8*)(srcp + j * 8);
      }
      __syncthreads();
    }
  }
}

// ---------------------------------------------------------------- attention (split-KV chunks)
// grid 1024: id -> (b = id>>8, qt = (id>>2)&63, ci = id&3). chunk ci covers
// kv-tiles [ci*16, min(ci*16+16, qt+1)). ci > qt>>4 -> empty. No online max:
// partial numerators/denominators combine linearly in attn_reduce.
__launch_bounds__(256)
__global__ void attn_chunk(const u16* __restrict__ qb,
                           const u16* __restrict__ kb,
                           const u16* __restrict__ vt,
                           float* __restrict__ pO,
                           float* __restrict__ pR)
{
  const int id = blockIdx.x;
  const int b  = id >> 8;
  const int qt = (id >> 2) & 63;
  const int ci = id & 3;
  const int G  = qt >> 4;
  if (ci > G) return;
  const int slot = b * 160 + 8 * G * (G + 1) + (qt - 16 * G) * (G + 1) + ci;
  const int q0 = qt * 32;
  const int kvt_beg = ci * 16;
  const int kvt_end = (kvt_beg + 16 < qt + 1) ? kvt_beg + 16 : qt + 1;

  __shared__ alignas(16) float Sp[4][32][36];
  __shared__ alignas(16) u16 Pl[32][32];

  const int tid = threadIdx.x;
  const int l = tid & 63, w = tid >> 6;
  const int lr = l & 15, lg = l >> 4;

  short8 qf[2][4];
  {
    const u16* qbase = qb + (size_t)(b * S_LEN + q0) * D_DIM + w * 128;
#pragma unroll
    for (int mf = 0; mf < 2; mf++)
#pragma unroll
      for (int kk = 0; kk < 4; kk++)
        qf[mf][kk] = *(const short8*)(qbase + (size_t)(mf * 16 + lr) * D_DIM + kk * 32 + lg * 8);
  }

  floatx4 of[2][8];
#pragma unroll
  for (int mf = 0; mf < 2; mf++)
#pragma unroll
    for (int nf = 0; nf < 8; nf++) of[mf][nf] = 0.0f;

  float rsum = 0.f;
  const int srow = tid >> 3;
  const int sc0 = (tid & 7) * 4;

  const u16* kbb = kb + (size_t)b * S_LEN * D_DIM + w * 128;
  const u16* vtb = vt + (size_t)b * D_DIM * S_LEN + (size_t)(w * 128) * S_LEN;

  for (int kvt = kvt_beg; kvt < kvt_end; ++kvt) {
    const int kv0 = kvt * 32;
    floatx4 sa[2][2];
    sa[0][0] = 0.0f; sa[0][1] = 0.0f; sa[1][0] = 0.0f; sa[1][1] = 0.0f;
#pragma unroll
    for (int nf = 0; nf < 2; nf++) {
#pragma unroll
      for (int kk = 0; kk < 4; kk++) {
        short8 kf = *(const short8*)(kbb + (size_t)(kv0 + nf * 16 + lr) * D_DIM + kk * 32 + lg * 8);
        sa[0][nf] = mfma16(qf[0][kk], kf, sa[0][nf]);
        sa[1][nf] = mfma16(qf[1][kk], kf, sa[1][nf]);
      }
    }
#pragma unroll
    for (int mf = 0; mf < 2; mf++)
#pragma unroll
      for (int nf = 0; nf < 2; nf++)
#pragma unroll
        for (int r = 0; r < 4; r++)
          Sp[w][mf * 16 + lg * 4 + r][nf * 16 + lr] = sa[mf][nf][r];
    __syncthreads();
    {
      float4 s = make_float4(0.f, 0.f, 0.f, 0.f);
#pragma unroll
      for (int ww = 0; ww < 4; ww++) {
        float4 t = *(const float4*)&Sp[ww][srow][sc0];
        s.x += t.x; s.y += t.y; s.z += t.z; s.w += t.w;
      }
      float p0, p1, p2, p3;
      if (kvt == qt) {
        const int qrow = q0 + srow;
        p0 = (kv0 + sc0 + 0 <= qrow) ? __expf(s.x) : 0.f;
        p1 = (kv0 + sc0 + 1 <= qrow) ? __expf(s.y) : 0.f;
        p2 = (kv0 + sc0 + 2 <= qrow) ? __expf(s.z) : 0.f;
        p3 = (kv0 + sc0 + 3 <= qrow) ? __expf(s.w) : 0.f;
      } else {
        p0 = __expf(s.x); p1 = __expf(s.y); p2 = __expf(s.z); p3 = __expf(s.w);
      }
      rsum += p0 + p1 + p2 + p3;
      ushort4 pk;
      pk.x = f2b(p0); pk.y = f2b(p1); pk.z = f2b(p2); pk.w = f2b(p3);
      *(ushort4*)&Pl[srow][sc0] = pk;
    }
    __syncthreads();
    short8 pf0 = *(const short8*)&Pl[lr][lg * 8];
    short8 pf1 = *(const short8*)&Pl[16 + lr][lg * 8];
#pragma unroll
    for (int nf = 0; nf < 8; nf++) {
      short8 vf = *(const short8*)(vtb + (size_t)(nf * 16 + lr) * S_LEN + kv0 + lg * 8);
      of[0][nf] = mfma16(pf0, vf, of[0][nf]);
      of[1][nf] = mfma16(pf1, vf, of[1][nf]);
    }
  }

  // partial denominator
  rsum += __shfl_xor(rsum, 1);
  rsum += __shfl_xor(rsum, 2);
  rsum += __shfl_xor(rsum, 4);
  if ((tid & 7) == 0) pR[slot * 32 + (tid >> 3)] = rsum;

  // partial numerator
  float* po = pO + (size_t)slot * 32 * 512;
#pragma unroll
  for (int mf = 0; mf < 2; mf++)
#pragma unroll
    for (int r = 0; r < 4; r++) {
      const int row = mf * 16 + lg * 4 + r;
      float* op = po + (size_t)row * 512 + w * 128 + lr;
#pragma unroll
      for (int nf = 0; nf < 8; nf++)
        op[nf * 16] = of[mf][nf][r];
    }
}

// ---------------------------------------------------------------- reduce partials
__launch_bounds__(256)
__global__ void attn_reduce(const float* __restrict__ pO,
                            const float* __restrict__ pR,
                            float* __restrict__ out)
{
  const int id = blockIdx.x;           // b*64 + qt
  const int b = id >> 6, qt = id & 63;
  const int G = qt >> 4;
  const int nc = G + 1;
  const int slot0 = b * 160 + 8 * G * (G + 1) + (qt - 16 * G) * (G + 1);
  const int row = threadIdx.x >> 3;
  const int c0 = (threadIdx.x & 7) * 64;

  float rsum = 0.f;
  for (int ci = 0; ci < nc; ci++) rsum += pR[(slot0 + ci) * 32 + row];
  const float inv = 1.0f / rsum;

  float4 acc[16];
  const float* src = pO + ((size_t)slot0 * 32 + row) * 512 + c0;
#pragma unroll
  for (int j = 0; j < 16; j++) acc[j] = *(const float4*)(src + j * 4);
  for (int ci = 1; ci < nc; ci++) {
    const float* s2 = src + (size_t)ci * 32 * 512;
#pragma unroll
    for (int j = 0; j < 16; j++) {
      float4 t = *(const float4*)(s2 + j * 4);
      acc[j].x += t.x; acc[j].y += t.y; acc[j].z += t.z; acc[j].w += t.w;
    }
  }
  float* dst = out + ((size_t)(b * S_LEN + qt * 32 + row)) * 512 + c0;
#pragma unroll
  for (int j = 0; j < 16; j++) {
    float4 t;
    t.x = acc[j].x * inv; t.y = acc[j].y * inv;
    t.z = acc[j].z * inv; t.w = acc[j].w * inv;
    *(float4*)(dst + j * 4) = t;
  }
}

// ---------------------------------------------------------------- launch
extern "C" void kernel_launch(void* const* d_in, const int* in_sizes, int n_in,
                              void* d_out, int out_size, void* d_ws, size_t ws_size,
                              hipStream_t stream)
{
  const float* x  = (const float*)d_in[0];
  const float* Wq = (const float*)d_in[1];
  const float* bq = (const float*)d_in[2];
  const float* Wk = (const float*)d_in[3];
  const float* bk = (const float*)d_in[4];
  const float* Wv = (const float*)d_in[5];
  const float* bv = (const float*)d_in[6];
  float* out = (float*)d_out;

  u16* xw = (u16*)d_ws;
  u16* xb = xw;                              // [8192][512] bf16
  u16* wb = xb + (size_t)NROWS * D_DIM;      // [1536][512] bf16
  u16* qb = wb + (size_t)NQKV * D_DIM;       // [8192][512] bf16 (scaled)
  u16* kb = qb + (size_t)NROWS * D_DIM;      // [8192][512] bf16
  u16* vt = kb + (size_t)NROWS * D_DIM;      // [4][512][2048] bf16 (V^T)
  float* pO = (float*)(vt + (size_t)NROWS * D_DIM);  // [640][32][512] f32 partial numerators
  float* pR = pO + (size_t)640 * 32 * 512;           // [640][32] f32 partial denominators

  hipLaunchKernelGGL(cvt_kernel, dim3(2048), dim3(256), 0, stream, x, Wq, Wk, Wv, xw);
  hipLaunchKernelGGL(qkv_gemm, dim3(768), dim3(256), 0, stream,
                     xb, wb, bq, bk, bv, qb, kb, vt);
  hipLaunchKernelGGL(attn_chunk, dim3(1024), dim3(256), 0, stream, qb, kb, vt, pO, pR);
  hipLaunchKernelGGL(attn_reduce, dim3(256), dim3(256), 0, stream, pO, pR, out);
}

// Round 3
// 141.574 us; speedup vs baseline: 1.6641x; 1.6641x over previous
//
#include <hip/hip_runtime.h>
#include <hip/hip_bf16.h>
#include <cstdint>

#define S_LEN 2048
#define D_DIM 512
#define NROWS 8192           // B*S
#define NQKV  1536           // 3*512 output cols of the fused projection
#define QK_SCALE 0.04419417382415922f   // 1/sqrt(512)

typedef unsigned short u16;
typedef __attribute__((ext_vector_type(8))) short short8;
typedef __attribute__((ext_vector_type(4))) float floatx4;

__device__ inline floatx4 mfma16(short8 a, short8 b, floatx4 c){
  return __builtin_amdgcn_mfma_f32_16x16x32_bf16(a, b, c, 0, 0, 0);
}
__device__ inline u16 f2b(float f){
  uint32_t u = __float_as_uint(f);
  u = (u + 0x7fffu + ((u >> 16) & 1u)) >> 16;
  return (u16)u;
}
__device__ inline float b2f(u16 u){ return __uint_as_float(((uint32_t)u) << 16); }
#define GLD16(g, l) __builtin_amdgcn_global_load_lds( \
    (const __attribute__((address_space(1))) void*)(g), \
    (__attribute__((address_space(3))) void*)(l), 16, 0, 0)

// ---------------------------------------------------------------- convert
__global__ void cvt_kernel(const float* __restrict__ x,
                           const float* __restrict__ Wq,
                           const float* __restrict__ Wk,
                           const float* __restrict__ Wv,
                           u16* __restrict__ xw)
{
  const int NT4 = (NROWS * D_DIM) / 4 + (NQKV * D_DIM) / 4;
  for (int i = blockIdx.x * blockDim.x + threadIdx.x; i < NT4;
       i += gridDim.x * blockDim.x) {
    int e = i * 4;
    const float* src;
    if (e < NROWS * D_DIM) {
      src = x + e;
    } else {
      int j = e - NROWS * D_DIM;
      if (j < 512 * 512)           src = Wq + j;
      else if (j < 2 * 512 * 512)  src = Wk + (j - 512 * 512);
      else                         src = Wv + (j - 2 * 512 * 512);
    }
    float4 v = *(const float4*)src;
    ushort4 o;
    o.x = f2b(v.x); o.y = f2b(v.y); o.z = f2b(v.z); o.w = f2b(v.w);
    *(ushort4*)(xw + e) = o;
  }
}

// ---------------------------------------------------------------- QKV GEMM
__launch_bounds__(256)
__global__ void qkv_gemm(const u16* __restrict__ xb,
                         const u16* __restrict__ wb,
                         const float* __restrict__ bq,
                         const float* __restrict__ bk,
                         const float* __restrict__ bv,
                         u16* __restrict__ qb,
                         u16* __restrict__ kb,
                         u16* __restrict__ vt)
{
  __shared__ alignas(16) u16 sm[16384];   // lA[128][64] @0, lB[128][64] @8192
  const int tid = threadIdx.x;
  const int l = tid & 63, w = tid >> 6;
  const int lr = l & 15, lg = l >> 4;
  const int wr = w >> 1, wc = w & 1;
  const int bn = blockIdx.x % 12, bm = blockIdx.x / 12;
  const int m0 = bm * 128, n0 = bn * 128;

  const u16* gA = xb + (size_t)(m0 + (tid >> 3)) * D_DIM + (tid & 7) * 8;
  const u16* gB = wb + (size_t)(n0 + (tid >> 3)) * D_DIM + (tid & 7) * 8;
  char* lA0 = (char*)&sm[0] + tid * 16;
  char* lB0 = (char*)&sm[8192] + tid * 16;

  floatx4 acc[4][4];
#pragma unroll
  for (int m = 0; m < 4; m++)
#pragma unroll
    for (int n = 0; n < 4; n++) acc[m][n] = 0.0f;

  for (int kt = 0; kt < 8; ++kt) {
    __syncthreads();
#pragma unroll
    for (int j = 0; j < 4; j++) {
      GLD16(gA + (size_t)j * 32 * D_DIM, lA0 + j * 4096);
      GLD16(gB + (size_t)j * 32 * D_DIM, lB0 + j * 4096);
    }
    gA += 64; gB += 64;
    __syncthreads();
#pragma unroll
    for (int kk = 0; kk < 2; ++kk) {
      short8 a[4], bfr[4];
#pragma unroll
      for (int m = 0; m < 4; m++)
        a[m] = *(const short8*)&sm[(wr * 64 + m * 16 + lr) * 64 + kk * 32 + lg * 8];
#pragma unroll
      for (int n = 0; n < 4; n++)
        bfr[n] = *(const short8*)&sm[8192 + (wc * 64 + n * 16 + lr) * 64 + kk * 32 + lg * 8];
#pragma unroll
      for (int m = 0; m < 4; m++)
#pragma unroll
        for (int n = 0; n < 4; n++)
          acc[m][n] = mfma16(a[m], bfr[n], acc[m][n]);
    }
  }

  if (n0 < 1024) {
    const float* bias = (n0 < 512) ? bq : bk;
    u16* dst = (n0 < 512) ? qb : kb;
    const float scl = (n0 < 512) ? QK_SCALE : 1.0f;
    const int nbase = n0 & 511;
#pragma unroll
    for (int n = 0; n < 4; n++) {
      int gn = nbase + wc * 64 + n * 16 + lr;
      float bia = bias[gn];
#pragma unroll
      for (int m = 0; m < 4; m++) {
        int gm0 = m0 + wr * 64 + m * 16 + lg * 4;
#pragma unroll
        for (int r = 0; r < 4; r++)
          dst[(size_t)(gm0 + r) * D_DIM + gn] = f2b((acc[m][n][r] + bia) * scl);
      }
    }
  } else {
    const int nbase = n0 - 1024;
    const int bIdx = m0 >> 11;
    const int s0 = m0 & 2047;
    __syncthreads();
#pragma unroll
    for (int h = 0; h < 2; ++h) {
      if (wc == h) {
#pragma unroll
        for (int n = 0; n < 4; n++) {
          int lrow = n * 16 + lr;
          float bia = bv[nbase + h * 64 + lrow];
#pragma unroll
          for (int m = 0; m < 4; m++) {
            int lcol = wr * 64 + m * 16 + lg * 4;
#pragma unroll
            for (int r = 0; r < 4; r++)
              sm[lrow * 136 + lcol + r] = f2b(acc[m][n][r] + bia);
          }
        }
      }
      __syncthreads();
      {
        int row = tid >> 2;
        int c0 = (tid & 3) * 32;
        u16* dstp = vt + (size_t)bIdx * D_DIM * S_LEN
                       + (size_t)(nbase + h * 64 + row) * S_LEN + s0 + c0;
        const u16* srcp = &sm[row * 136 + c0];
#pragma unroll
        for (int j = 0; j < 4; j++)
          *(short8*)(dstp + j * 8) = *(const short8*)(srcp + j * 8);
      }
      __syncthreads();
    }
  }
}

// ---------------------------------------------------------------- attention chunks
// QBLK=64 q-rows, 8 waves x D-slice 64, chunk = 16 kv-tiles (512 kv).
// Grid 352 = 8 XCD lanes x 44: batch b pinned to XCDs {2b,2b+1} so its
// 4MB K+V^T stays L2-resident. Partials stream out non-temporally.
__launch_bounds__(512)
__global__ void attn_chunk(const u16* __restrict__ qb,
                           const u16* __restrict__ kb,
                           const u16* __restrict__ vt,
                           float* __restrict__ pO,
                           float* __restrict__ pR)
{
  __shared__ alignas(16) u16 Sp[8][64][40];   // bf16 partial scores [wave][q][kv+pad]
  __shared__ alignas(16) u16 Pl[64][40];      // P bf16 [q][kv+pad]

  const int id = blockIdx.x;
  const int xl = id & 7, j = id >> 3;
  const int b = xl >> 1;
  const int c = (xl & 1) * 44 + j;
  if (c >= 80) return;
  const int g = (c < 8) ? 0 : (c < 24) ? 1 : (c < 48) ? 2 : 3;
  const int rr = c - 4 * g * (g + 1);
  const int qdiv = rr / (g + 1);
  const int qt = 8 * g + qdiv;
  const int ci = rr - qdiv * (g + 1);
  const int slot = b * 80 + c;
  const int q0 = qt * 64;
  const int kvt_beg = ci * 16;
  int kvt_end = 2 * qt + 2;
  if (kvt_beg + 16 < kvt_end) kvt_end = kvt_beg + 16;   // all lengths even

  const int tid = threadIdx.x;
  const int l = tid & 63, w = tid >> 6;
  const int lr = l & 15, lg = l >> 4;
  const int d0 = w * 64;

  short8 qf[4][2];
  {
    const u16* qbase = qb + (size_t)(b * S_LEN + q0) * D_DIM + d0;
#pragma unroll
    for (int nf = 0; nf < 4; nf++)
#pragma unroll
      for (int kk = 0; kk < 2; kk++)
        qf[nf][kk] = *(const short8*)(qbase + (size_t)(nf * 16 + lr) * D_DIM + kk * 32 + lg * 8);
  }

  floatx4 of[4][4];
#pragma unroll
  for (int i = 0; i < 4; i++)
#pragma unroll
    for (int nf = 0; nf < 4; nf++) of[i][nf] = 0.0f;

  float rsum = 0.f;
  const int srow = tid >> 3;         // 0..63
  const int sc0 = (tid & 7) * 4;     // 0..28

  const u16* kbb = kb + (size_t)b * S_LEN * D_DIM + d0;
  const u16* vtb = vt + (size_t)b * D_DIM * S_LEN + (size_t)d0 * S_LEN;

  short8 kfA[2][2], kfB[2][2];

#define LOADK(DST, KVT) { const int _kv0 = (KVT) * 32; \
  _Pragma("unroll") for (int mf = 0; mf < 2; mf++) \
  _Pragma("unroll") for (int kk = 0; kk < 2; kk++) \
    DST[mf][kk] = *(const short8*)(kbb + (size_t)(_kv0 + mf * 16 + lr) * D_DIM + kk * 32 + lg * 8); }

  LOADK(kfA, kvt_beg)

#define STEP(KVT, KC, KN, PN) { \
  const int kv0 = (KVT) * 32; \
  short8 vf[4]; \
  _Pragma("unroll") for (int nf = 0; nf < 4; nf++) \
    vf[nf] = *(const short8*)(vtb + (size_t)(nf * 16 + lr) * S_LEN + kv0 + lg * 8); \
  floatx4 sa[2][4]; \
  _Pragma("unroll") for (int mf = 0; mf < 2; mf++) \
  _Pragma("unroll") for (int nf = 0; nf < 4; nf++) sa[mf][nf] = 0.0f; \
  _Pragma("unroll") for (int kk = 0; kk < 2; kk++) \
  _Pragma("unroll") for (int mf = 0; mf < 2; mf++) \
  _Pragma("unroll") for (int nf = 0; nf < 4; nf++) \
    sa[mf][nf] = mfma16(KC[mf][kk], qf[nf][kk], sa[mf][nf]); \
  LOADK(KN, PN) \
  _Pragma("unroll") for (int mf = 0; mf < 2; mf++) \
  _Pragma("unroll") for (int nf = 0; nf < 4; nf++) { \
    ushort4 pk4; \
    pk4.x = f2b(sa[mf][nf][0]); pk4.y = f2b(sa[mf][nf][1]); \
    pk4.z = f2b(sa[mf][nf][2]); pk4.w = f2b(sa[mf][nf][3]); \
    *(ushort4*)&Sp[w][nf * 16 + lr][mf * 16 + lg * 4] = pk4; } \
  __syncthreads(); \
  { \
    float s0 = 0.f, s1 = 0.f, s2 = 0.f, s3 = 0.f; \
    _Pragma("unroll") for (int ww = 0; ww < 8; ww++) { \
      ushort4 t = *(const ushort4*)&Sp[ww][srow][sc0]; \
      s0 += b2f(t.x); s1 += b2f(t.y); s2 += b2f(t.z); s3 += b2f(t.w); } \
    const int qrow = q0 + srow; \
    float p0 = (kv0 + sc0 + 0 <= qrow) ? __expf(s0) : 0.f; \
    float p1 = (kv0 + sc0 + 1 <= qrow) ? __expf(s1) : 0.f; \
    float p2 = (kv0 + sc0 + 2 <= qrow) ? __expf(s2) : 0.f; \
    float p3 = (kv0 + sc0 + 3 <= qrow) ? __expf(s3) : 0.f; \
    rsum += p0 + p1 + p2 + p3; \
    ushort4 pk; pk.x = f2b(p0); pk.y = f2b(p1); pk.z = f2b(p2); pk.w = f2b(p3); \
    *(ushort4*)&Pl[srow][sc0] = pk; \
  } \
  __syncthreads(); \
  { \
    short8 pf[4]; \
    _Pragma("unroll") for (int i = 0; i < 4; i++) \
      pf[i] = *(const short8*)&Pl[i * 16 + lr][lg * 8]; \
    _Pragma("unroll") for (int i = 0; i < 4; i++) \
    _Pragma("unroll") for (int nf = 0; nf < 4; nf++) \
      of[i][nf] = mfma16(pf[i], vf[nf], of[i][nf]); \
  } }

  for (int kvt = kvt_beg; kvt < kvt_end; kvt += 2) {
    STEP(kvt, kfA, kfB, kvt + 1)
    const int pn2 = (kvt + 2 < kvt_end) ? kvt + 2 : kvt_end - 1;
    STEP(kvt + 1, kfB, kfA, pn2)
  }

  // partial denominator (threads sharing srow are lanes {8k..8k+7} of one wave)
  rsum += __shfl_xor(rsum, 1);
  rsum += __shfl_xor(rsum, 2);
  rsum += __shfl_xor(rsum, 4);
  if ((tid & 7) == 0)
    __builtin_nontemporal_store(rsum, &pR[slot * 64 + srow]);

  // partial numerator (non-temporal: keep K/V in L2)
  float* po = pO + (size_t)slot * (64 * 512);
#pragma unroll
  for (int i = 0; i < 4; i++)
#pragma unroll
    for (int r = 0; r < 4; r++) {
      const int row = i * 16 + lg * 4 + r;
      float* op = po + (size_t)row * 512 + d0 + lr;
#pragma unroll
      for (int nf = 0; nf < 4; nf++)
        __builtin_nontemporal_store(of[i][nf][r], op + nf * 16);
    }
#undef LOADK
#undef STEP
}

// ---------------------------------------------------------------- reduce partials
__launch_bounds__(256)
__global__ void attn_reduce(const float* __restrict__ pO,
                            const float* __restrict__ pR,
                            float* __restrict__ out)
{
  const int id = blockIdx.x;          // 0..255: b(2) x qt(5) x half(1)
  const int b = id >> 6;
  const int qt = (id >> 1) & 31;
  const int half = id & 1;
  const int g = qt >> 3;
  const int nc = g + 1;
  const int base = 4 * g * (g + 1) + (qt - 8 * g) * (g + 1);
  const int slot0 = b * 80 + base;
  const int row = half * 32 + (threadIdx.x >> 3);   // 0..63
  const int c0 = (threadIdx.x & 7) * 64;

  float rsum = 0.f;
  for (int ci = 0; ci < nc; ci++) rsum += pR[(slot0 + ci) * 64 + row];
  const float inv = 1.0f / rsum;

  float4 acc[16];
  const float* src = pO + ((size_t)slot0 * 64 + row) * 512 + c0;
#pragma unroll
  for (int t = 0; t < 16; t++) acc[t] = *(const float4*)(src + t * 4);
  for (int ci = 1; ci < nc; ci++) {
    const float* s2 = src + (size_t)ci * 64 * 512;
#pragma unroll
    for (int t = 0; t < 16; t++) {
      float4 v = *(const float4*)(s2 + t * 4);
      acc[t].x += v.x; acc[t].y += v.y; acc[t].z += v.z; acc[t].w += v.w;
    }
  }
  float* dst = out + (size_t)(b * S_LEN + qt * 64 + row) * 512 + c0;
#pragma unroll
  for (int t = 0; t < 16; t++) {
    float4 v;
    v.x = acc[t].x * inv; v.y = acc[t].y * inv;
    v.z = acc[t].z * inv; v.w = acc[t].w * inv;
    *(float4*)(dst + t * 4) = v;
  }
}

// ---------------------------------------------------------------- launch
extern "C" void kernel_launch(void* const* d_in, const int* in_sizes, int n_in,
                              void* d_out, int out_size, void* d_ws, size_t ws_size,
                              hipStream_t stream)
{
  const float* x  = (const float*)d_in[0];
  const float* Wq = (const float*)d_in[1];
  const float* bq = (const float*)d_in[2];
  const float* Wk = (const float*)d_in[3];
  const float* bk = (const float*)d_in[4];
  const float* Wv = (const float*)d_in[5];
  const float* bv = (const float*)d_in[6];
  float* out = (float*)d_out;

  u16* xw = (u16*)d_ws;
  u16* xb = xw;                              // [8192][512] bf16
  u16* wb = xb + (size_t)NROWS * D_DIM;      // [1536][512] bf16
  u16* qb = wb + (size_t)NQKV * D_DIM;       // [8192][512] bf16 (scaled)
  u16* kb = qb + (size_t)NROWS * D_DIM;      // [8192][512] bf16
  u16* vt = kb + (size_t)NROWS * D_DIM;      // [4][512][2048] bf16 (V^T)
  float* pO = (float*)(vt + (size_t)NROWS * D_DIM);  // [320][64][512] f32 partial numerators
  float* pR = pO + (size_t)320 * 64 * 512;           // [320][64] f32 partial denominators

  hipLaunchKernelGGL(cvt_kernel, dim3(2048), dim3(256), 0, stream, x, Wq, Wk, Wv, xw);
  hipLaunchKernelGGL(qkv_gemm, dim3(768), dim3(256), 0, stream,
                     xb, wb, bq, bk, bv, qb, kb, vt);
  hipLaunchKernelGGL(attn_chunk, dim3(352), dim3(512), 0, stream, qb, kb, vt, pO, pR);
  hipLaunchKernelGGL(attn_reduce, dim3(256), dim3(256), 0, stream, pO, pR, out);
}

// Round 4
// 113.803 us; speedup vs baseline: 2.0702x; 1.2440x over previous
//
#include <hip/hip_runtime.h>
#include <hip/hip_bf16.h>
#include <cstdint>

#define S_LEN 2048
#define D_DIM 512
#define NROWS 8192           // B*S
#define NQKV  1536           // 3*512 output cols of the fused projection
#define QK_SCALE 0.04419417382415922f   // 1/sqrt(512)

typedef unsigned short u16;
typedef __attribute__((ext_vector_type(8))) short short8;
typedef __attribute__((ext_vector_type(4))) float floatx4;

__device__ inline floatx4 mfma16(short8 a, short8 b, floatx4 c){
  return __builtin_amdgcn_mfma_f32_16x16x32_bf16(a, b, c, 0, 0, 0);
}
__device__ inline u16 f2b(float f){
  uint32_t u = __float_as_uint(f);
  u = (u + 0x7fffu + ((u >> 16) & 1u)) >> 16;
  return (u16)u;
}
__device__ inline float b2f(u16 u){ return __uint_as_float(((uint32_t)u) << 16); }
#define GLD16(g, l) __builtin_amdgcn_global_load_lds( \
    (const __attribute__((address_space(1))) void*)(g), \
    (__attribute__((address_space(3))) void*)(l), 16, 0, 0)
// barrier that does NOT drain vmcnt: keeps global prefetch loads in flight
#define BARRIER_LDS() asm volatile("s_waitcnt lgkmcnt(0)\n\ts_barrier" ::: "memory")

// ---------------------------------------------------------------- convert
__global__ void cvt_kernel(const float* __restrict__ x,
                           const float* __restrict__ Wq,
                           const float* __restrict__ Wk,
                           const float* __restrict__ Wv,
                           u16* __restrict__ xw)
{
  const int NT4 = (NROWS * D_DIM) / 4 + (NQKV * D_DIM) / 4;
  for (int i = blockIdx.x * blockDim.x + threadIdx.x; i < NT4;
       i += gridDim.x * blockDim.x) {
    int e = i * 4;
    const float* src;
    if (e < NROWS * D_DIM) {
      src = x + e;
    } else {
      int j = e - NROWS * D_DIM;
      if (j < 512 * 512)           src = Wq + j;
      else if (j < 2 * 512 * 512)  src = Wk + (j - 512 * 512);
      else                         src = Wv + (j - 2 * 512 * 512);
    }
    float4 v = *(const float4*)src;
    ushort4 o;
    o.x = f2b(v.x); o.y = f2b(v.y); o.z = f2b(v.z); o.w = f2b(v.w);
    *(ushort4*)(xw + e) = o;
  }
}

// ---------------------------------------------------------------- QKV GEMM
// 2-phase double-buffered LDS pipeline; blocks grouped so all 12 n-blocks of
// one A-panel (bm) land on XCD bm&7 -> A re-reads become L2 hits.
__launch_bounds__(256)
__global__ void qkv_gemm(const u16* __restrict__ xb,
                         const u16* __restrict__ wb,
                         const float* __restrict__ bq,
                         const float* __restrict__ bk,
                         const float* __restrict__ bv,
                         u16* __restrict__ qb,
                         u16* __restrict__ kb,
                         u16* __restrict__ vt)
{
  __shared__ alignas(16) u16 sm[2][16384];   // [buf][ A 128x64 | B 128x64 ]
  const int tid = threadIdx.x;
  const int l = tid & 63, w = tid >> 6;
  const int lr = l & 15, lg = l >> 4;
  const int wr = w >> 1, wc = w & 1;
  const int bid = blockIdx.x;
  const int xcd = bid & 7;
  const int t = bid >> 3;              // 0..95
  const int bn = t % 12, bmhi = t / 12;
  const int bm = (bmhi << 3) | xcd;    // A-panel pinned to XCD bm&7
  const int m0 = bm * 128, n0 = bn * 128;

  const u16* gA = xb + (size_t)(m0 + (tid >> 3)) * D_DIM + (tid & 7) * 8;
  const u16* gB = wb + (size_t)(n0 + (tid >> 3)) * D_DIM + (tid & 7) * 8;

#define STAGEK(BUF, KT) { \
  char* la = (char*)&sm[BUF][0] + tid * 16; \
  char* lb = (char*)&sm[BUF][8192] + tid * 16; \
  const u16* ga = gA + (KT) * 64; \
  const u16* gb = gB + (KT) * 64; \
  _Pragma("unroll") for (int jj = 0; jj < 4; jj++) { \
    GLD16(ga + (size_t)jj * 32 * D_DIM, la + jj * 4096); \
    GLD16(gb + (size_t)jj * 32 * D_DIM, lb + jj * 4096); } }

  floatx4 acc[4][4];
#pragma unroll
  for (int m = 0; m < 4; m++)
#pragma unroll
    for (int n = 0; n < 4; n++) acc[m][n] = 0.0f;

  STAGEK(0, 0)
  __syncthreads();

  for (int kt = 0; kt < 8; ++kt) {
    const int cb = kt & 1;
    if (kt < 7) STAGEK(cb ^ 1, kt + 1)
#pragma unroll
    for (int kk = 0; kk < 2; ++kk) {
      short8 a[4], bfr[4];
#pragma unroll
      for (int m = 0; m < 4; m++)
        a[m] = *(const short8*)&sm[cb][(wr * 64 + m * 16 + lr) * 64 + kk * 32 + lg * 8];
#pragma unroll
      for (int n = 0; n < 4; n++)
        bfr[n] = *(const short8*)&sm[cb][8192 + (wc * 64 + n * 16 + lr) * 64 + kk * 32 + lg * 8];
#pragma unroll
      for (int m = 0; m < 4; m++)
#pragma unroll
        for (int n = 0; n < 4; n++)
          acc[m][n] = mfma16(a[m], bfr[n], acc[m][n]);
    }
    __syncthreads();   // staged kt+1 complete + everyone done with buf cb
  }
#undef STAGEK

  if (n0 < 1024) {
    const float* bias = (n0 < 512) ? bq : bk;
    u16* dst = (n0 < 512) ? qb : kb;
    const float scl = (n0 < 512) ? QK_SCALE : 1.0f;
    const int nbase = n0 & 511;
#pragma unroll
    for (int n = 0; n < 4; n++) {
      int gn = nbase + wc * 64 + n * 16 + lr;
      float bia = bias[gn];
#pragma unroll
      for (int m = 0; m < 4; m++) {
        int gm0 = m0 + wr * 64 + m * 16 + lg * 4;
#pragma unroll
        for (int r = 0; r < 4; r++)
          dst[(size_t)(gm0 + r) * D_DIM + gn] = f2b((acc[m][n][r] + bia) * scl);
      }
    }
  } else {
    const int nbase = n0 - 1024;
    const int bIdx = m0 >> 11;
    const int s0 = m0 & 2047;
    __syncthreads();
#pragma unroll
    for (int h = 0; h < 2; ++h) {
      if (wc == h) {
#pragma unroll
        for (int n = 0; n < 4; n++) {
          int lrow = n * 16 + lr;
          float bia = bv[nbase + h * 64 + lrow];
#pragma unroll
          for (int m = 0; m < 4; m++) {
            int lcol = wr * 64 + m * 16 + lg * 4;
#pragma unroll
            for (int r = 0; r < 4; r++)
              sm[0][lrow * 136 + lcol + r] = f2b(acc[m][n][r] + bia);
          }
        }
      }
      __syncthreads();
      {
        int row = tid >> 2;
        int c0 = (tid & 3) * 32;
        u16* dstp = vt + (size_t)bIdx * D_DIM * S_LEN
                       + (size_t)(nbase + h * 64 + row) * S_LEN + s0 + c0;
        const u16* srcp = &sm[0][row * 136 + c0];
#pragma unroll
        for (int jj = 0; jj < 4; jj++)
          *(short8*)(dstp + jj * 8) = *(const short8*)(srcp + jj * 8);
      }
      __syncthreads();
    }
  }
}

// ---------------------------------------------------------------- attention chunks
// Uniform schedule: pair (p, 31-p) -> 66 kv-tiles concat, split into 4 chunks
// {17,17,16,16}. 256 blocks exactly, 16-17 steps each, zero idle blocks.
// Batch b pinned to XCDs {2b,2b+1}. Barriers do not drain vmcnt -> K/V
// prefetch stays in flight across the whole step.
__launch_bounds__(512)
__global__ void attn_chunk(const u16* __restrict__ qb,
                           const u16* __restrict__ kb,
                           const u16* __restrict__ vt,
                           float* __restrict__ pO,
                           float* __restrict__ pR)
{
  __shared__ alignas(16) u16 Sp[8][64][40];   // bf16 partial scores [wave][q][kv+pad]
  __shared__ alignas(16) u16 Pl[64][40];      // P bf16 [q][kv+pad]

  const int bid = blockIdx.x;
  const int xcd = bid & 7, b = xcd >> 1, xl = xcd & 1;
  const int rr = bid >> 3;                    // 0..31
  const int p = rr & 15;
  const int j = ((rr >> 4) << 1) | xl;        // chunk 0..3
  const int TA = 2 * p + 2;                   // kv-tiles of q-tile p
  const int gbeg = 17 * j - (j > 2 ? j - 2 : 0);
  const int gend = 17 * (j + 1) - (j >= 2 ? j - 1 : 0);

  const int tid = threadIdx.x;
  const int l = tid & 63, w = tid >> 6;
  const int lr = l & 15, lg = l >> 4;
  const int d0 = w * 64;
  const int srow = tid >> 3;         // 0..63
  const int sc0 = (tid & 7) * 4;     // 0..28

  const u16* kbb = kb + (size_t)b * S_LEN * D_DIM + d0;
  const u16* vtb = vt + (size_t)b * D_DIM * S_LEN + (size_t)d0 * S_LEN;

  short8 qf[4][2];
  floatx4 of[4][4];
  float rsum;
  int q0cur;

  auto loadQ = [&](int qt) {
    const u16* qbase = qb + (size_t)(b * S_LEN + qt * 64) * D_DIM + d0;
#pragma unroll
    for (int nf = 0; nf < 4; nf++)
#pragma unroll
      for (int kk = 0; kk < 2; kk++)
        qf[nf][kk] = *(const short8*)(qbase + (size_t)(nf * 16 + lr) * D_DIM + kk * 32 + lg * 8);
  };
  auto zeroAcc = [&]() {
#pragma unroll
    for (int i = 0; i < 4; i++)
#pragma unroll
      for (int nf = 0; nf < 4; nf++) of[i][nf] = 0.0f;
    rsum = 0.f;
  };
  auto flush = [&](int seg) {
    float rs = rsum;
    rs += __shfl_xor(rs, 1); rs += __shfl_xor(rs, 2); rs += __shfl_xor(rs, 4);
    const int slot = bid * 2 + seg;
    if ((tid & 7) == 0)
      __builtin_nontemporal_store(rs, &pR[slot * 64 + srow]);
    float* po = pO + (size_t)slot * (64 * 512);
#pragma unroll
    for (int i = 0; i < 4; i++)
#pragma unroll
      for (int r = 0; r < 4; r++) {
        const int row = i * 16 + lg * 4 + r;
        float* op = po + (size_t)row * 512 + d0 + lr;
#pragma unroll
        for (int nf = 0; nf < 4; nf++)
          __builtin_nontemporal_store(of[i][nf][r], op + nf * 16);
      }
  };

  short8 kfA[2][2], kfB[2][2];

#define LOADK(DST, KV) { const int _kv0 = (KV) * 32; \
  _Pragma("unroll") for (int mf = 0; mf < 2; mf++) \
  _Pragma("unroll") for (int kk = 0; kk < 2; kk++) \
    DST[mf][kk] = *(const short8*)(kbb + (size_t)(_kv0 + mf * 16 + lr) * D_DIM + kk * 32 + lg * 8); }

#define STEP(KC, KN) { \
  const int kv0 = kv * 32; \
  short8 vf[4]; \
  _Pragma("unroll") for (int nf = 0; nf < 4; nf++) \
    vf[nf] = *(const short8*)(vtb + (size_t)(nf * 16 + lr) * S_LEN + kv0 + lg * 8); \
  floatx4 sa[2][4]; \
  _Pragma("unroll") for (int mf = 0; mf < 2; mf++) \
  _Pragma("unroll") for (int nf = 0; nf < 4; nf++) sa[mf][nf] = 0.0f; \
  _Pragma("unroll") for (int kk = 0; kk < 2; kk++) \
  _Pragma("unroll") for (int mf = 0; mf < 2; mf++) \
  _Pragma("unroll") for (int nf = 0; nf < 4; nf++) \
    sa[mf][nf] = mfma16(KC[mf][kk], qf[nf][kk], sa[mf][nf]); \
  { const int gn = (g + 1 < gend) ? g + 1 : g; \
    const int kvn = (gn < TA) ? gn : gn - TA; \
    LOADK(KN, kvn) } \
  _Pragma("unroll") for (int mf = 0; mf < 2; mf++) \
  _Pragma("unroll") for (int nf = 0; nf < 4; nf++) { \
    ushort4 pk4; \
    pk4.x = f2b(sa[mf][nf][0]); pk4.y = f2b(sa[mf][nf][1]); \
    pk4.z = f2b(sa[mf][nf][2]); pk4.w = f2b(sa[mf][nf][3]); \
    *(ushort4*)&Sp[w][nf * 16 + lr][mf * 16 + lg * 4] = pk4; } \
  BARRIER_LDS(); \
  { \
    float s0 = 0.f, s1 = 0.f, s2 = 0.f, s3 = 0.f; \
    _Pragma("unroll") for (int ww = 0; ww < 8; ww++) { \
      ushort4 tt = *(const ushort4*)&Sp[ww][srow][sc0]; \
      s0 += b2f(tt.x); s1 += b2f(tt.y); s2 += b2f(tt.z); s3 += b2f(tt.w); } \
    float p0 = __expf(s0), p1 = __expf(s1), p2 = __expf(s2), p3 = __expf(s3); \
    if (diag) { \
      const int qrow = q0cur + srow; \
      p0 = (kv0 + sc0 + 0 <= qrow) ? p0 : 0.f; \
      p1 = (kv0 + sc0 + 1 <= qrow) ? p1 : 0.f; \
      p2 = (kv0 + sc0 + 2 <= qrow) ? p2 : 0.f; \
      p3 = (kv0 + sc0 + 3 <= qrow) ? p3 : 0.f; } \
    ushort4 pk; pk.x = f2b(p0); pk.y = f2b(p1); pk.z = f2b(p2); pk.w = f2b(p3); \
    *(ushort4*)&Pl[srow][sc0] = pk; \
    rsum += b2f(pk.x) + b2f(pk.y) + b2f(pk.z) + b2f(pk.w); \
  } \
  BARRIER_LDS(); \
  { \
    short8 pf[4]; \
    _Pragma("unroll") for (int i = 0; i < 4; i++) \
      pf[i] = *(const short8*)&Pl[i * 16 + lr][lg * 8]; \
    _Pragma("unroll") for (int i = 0; i < 4; i++) \
    _Pragma("unroll") for (int nf = 0; nf < 4; nf++) \
      of[i][nf] = mfma16(pf[i], vf[nf], of[i][nf]); \
  } }

  int seg_qt = (gbeg < TA) ? p : 31 - p;
  q0cur = seg_qt * 64;
  loadQ(seg_qt);
  zeroAcc();
  { const int kvi = (gbeg < TA) ? gbeg : gbeg - TA;
    LOADK(kfA, kvi) }

  int g = gbeg;
  while (g < gend) {
    if (g == TA && gbeg < TA) {
      flush(0);
      seg_qt = 31 - p; q0cur = seg_qt * 64;
      loadQ(seg_qt); zeroAcc();
    }
    { const int kv = (g < TA) ? g : g - TA;
      const int tot = (g < TA) ? TA : 66 - TA;
      const bool diag = (kv >= tot - 2);
      STEP(kfA, kfB) }
    ++g;
    if (g >= gend) break;
    if (g == TA && gbeg < TA) {
      flush(0);
      seg_qt = 31 - p; q0cur = seg_qt * 64;
      loadQ(seg_qt); zeroAcc();
    }
    { const int kv = (g < TA) ? g : g - TA;
      const int tot = (g < TA) ? TA : 66 - TA;
      const bool diag = (kv >= tot - 2);
      STEP(kfB, kfA) }
    ++g;
  }
  flush((seg_qt == p) ? 0 : 1);
#undef LOADK
#undef STEP
}

// ---------------------------------------------------------------- reduce partials
__launch_bounds__(256)
__global__ void attn_reduce(const float* __restrict__ pO,
                            const float* __restrict__ pR,
                            float* __restrict__ out)
{
  const int id = blockIdx.x;          // b(2) x qt(5) x half(1)
  const int b = id >> 6;
  const int qt = (id >> 1) & 31;
  const int half = id & 1;
  const int p = (qt < 16) ? qt : 31 - qt;
  const bool isA = (qt < 16);
  const int TA = 2 * p + 2;

  int slots[4]; int ns = 0;
#pragma unroll
  for (int j = 0; j < 4; j++) {
    const int sj = 17 * j - (j > 2 ? j - 2 : 0);
    const int ej = 17 * (j + 1) - (j >= 2 ? j - 1 : 0);
    const bool c = isA ? (sj < TA) : (ej > TA);
    if (c) {
      const int rr2 = ((j >> 1) << 4) | p;
      const int bidc = (rr2 << 3) | (b << 1) | (j & 1);
      slots[ns++] = bidc * 2 + (isA ? 0 : 1);
    }
  }

  const int row = half * 32 + (threadIdx.x >> 3);   // 0..63
  const int c0 = (threadIdx.x & 7) * 64;

  float rsum = 0.f;
  for (int s = 0; s < ns; s++) rsum += pR[slots[s] * 64 + row];
  const float inv = 1.0f / rsum;

  float4 acc[16];
#pragma unroll
  for (int t = 0; t < 16; t++) { acc[t].x = 0.f; acc[t].y = 0.f; acc[t].z = 0.f; acc[t].w = 0.f; }
  for (int s = 0; s < ns; s++) {
    const float* src = pO + ((size_t)slots[s] * 64 + row) * 512 + c0;
#pragma unroll
    for (int t = 0; t < 16; t++) {
      float4 v = *(const float4*)(src + t * 4);
      acc[t].x += v.x; acc[t].y += v.y; acc[t].z += v.z; acc[t].w += v.w;
    }
  }
  float* dst = out + (size_t)(b * S_LEN + qt * 64 + row) * 512 + c0;
#pragma unroll
  for (int t = 0; t < 16; t++) {
    float4 v;
    v.x = acc[t].x * inv; v.y = acc[t].y * inv;
    v.z = acc[t].z * inv; v.w = acc[t].w * inv;
    *(float4*)(dst + t * 4) = v;
  }
}

// ---------------------------------------------------------------- launch
extern "C" void kernel_launch(void* const* d_in, const int* in_sizes, int n_in,
                              void* d_out, int out_size, void* d_ws, size_t ws_size,
                              hipStream_t stream)
{
  const float* x  = (const float*)d_in[0];
  const float* Wq = (const float*)d_in[1];
  const float* bq = (const float*)d_in[2];
  const float* Wk = (const float*)d_in[3];
  const float* bk = (const float*)d_in[4];
  const float* Wv = (const float*)d_in[5];
  const float* bv = (const float*)d_in[6];
  float* out = (float*)d_out;

  u16* xw = (u16*)d_ws;
  u16* xb = xw;                              // [8192][512] bf16
  u16* wb = xb + (size_t)NROWS * D_DIM;      // [1536][512] bf16
  u16* qb = wb + (size_t)NQKV * D_DIM;       // [8192][512] bf16 (scaled)
  u16* kb = qb + (size_t)NROWS * D_DIM;      // [8192][512] bf16
  u16* vt = kb + (size_t)NROWS * D_DIM;      // [4][512][2048] bf16 (V^T)
  float* pO = (float*)(vt + (size_t)NROWS * D_DIM);  // [512][64][512] f32 partial numerators
  float* pR = pO + (size_t)512 * 64 * 512;           // [512][64] f32 partial denominators

  hipLaunchKernelGGL(cvt_kernel, dim3(2048), dim3(256), 0, stream, x, Wq, Wk, Wv, xw);
  hipLaunchKernelGGL(qkv_gemm, dim3(768), dim3(256), 0, stream,
                     xb, wb, bq, bk, bv, qb, kb, vt);
  hipLaunchKernelGGL(attn_chunk, dim3(256), dim3(512), 0, stream, qb, kb, vt, pO, pR);
  hipLaunchKernelGGL(attn_reduce, dim3(256), dim3(256), 0, stream, pO, pR, out);
}